// Round 7
// baseline (433.537 us; speedup 1.0000x reference)
//
#include <hip/hip_runtime.h>
#include <hip/hip_fp16.h>

using f16x8 = __attribute__((ext_vector_type(8))) _Float16;
using f32x4 = __attribute__((ext_vector_type(4))) float;
using f32x2 = __attribute__((ext_vector_type(2))) float;

// ---------------- wave helpers (wave = 64 lanes on CDNA) ----------------
static __device__ __forceinline__ float wred_max(float v) {
#pragma unroll
  for (int o = 32; o > 0; o >>= 1) v = fmaxf(v, __shfl_xor(v, o));
  return v;
}
static __device__ __forceinline__ float wred_sum(float v) {
#pragma unroll
  for (int o = 32; o > 0; o >>= 1) v += __shfl_xor(v, o);
  return v;
}
static __device__ __forceinline__ float lrelu(float x) { return x > 0.f ? x : 0.2f * x; }

// ---------------- preprocessing: CSR build ----------------
__global__ void zero_int2(int* __restrict__ a, int* __restrict__ b, int n) {
  int i = blockIdx.x * blockDim.x + threadIdx.x;
  if (i < n) { a[i] = 0; b[i] = 0; }
}

__global__ void count_deg(const int* __restrict__ dst, int* __restrict__ deg, int E) {
  int i = blockIdx.x * blockDim.x + threadIdx.x;
  if (i < E) atomicAdd(&deg[dst[i]], 1);
}

// ---------------- multi-block exclusive scan (3 kernels) ----------------
__global__ __launch_bounds__(256) void scan_part(const int* __restrict__ deg,
                                                 int* __restrict__ bsum, int n) {
  __shared__ int sd[256];
  int tid = threadIdx.x;
  int i = blockIdx.x * 256 + tid;
  sd[tid] = (i < n) ? deg[i] : 0;
  __syncthreads();
#pragma unroll
  for (int d = 128; d > 0; d >>= 1) {
    if (tid < d) sd[tid] += sd[tid + d];
    __syncthreads();
  }
  if (tid == 0) bsum[blockIdx.x] = sd[0];
}

__global__ __launch_bounds__(256) void scan_bsum(const int* __restrict__ bsum,
                                                 int* __restrict__ boff, int nb) {
  __shared__ int sd[256];
  int tid = threadIdx.x;
  int v = (tid < nb) ? bsum[tid] : 0;
  sd[tid] = v;
  __syncthreads();
#pragma unroll
  for (int d = 1; d < 256; d <<= 1) {
    int t = (tid >= d) ? sd[tid - d] : 0;
    __syncthreads();
    sd[tid] += t;
    __syncthreads();
  }
  if (tid < nb) boff[tid] = sd[tid] - v;  // exclusive
}

__global__ __launch_bounds__(256) void scan_final(const int* __restrict__ deg,
                                                  const int* __restrict__ boff,
                                                  int* __restrict__ row_start, int n) {
  __shared__ int sd[256];
  int tid = threadIdx.x;
  int i = blockIdx.x * 256 + tid;
  int v = (i < n) ? deg[i] : 0;
  sd[tid] = v;
  __syncthreads();
#pragma unroll
  for (int d = 1; d < 256; d <<= 1) {
    int t = (tid >= d) ? sd[tid - d] : 0;
    __syncthreads();
    sd[tid] += t;
    __syncthreads();
  }
  int incl = sd[tid];
  int base = boff[blockIdx.x];
  if (i < n) row_start[i] = base + incl - v;
  if (i == n - 1) row_start[n] = base + incl;
}

__global__ void scatter_edges(const int* __restrict__ src, const int* __restrict__ dst,
                              const int* __restrict__ row_start, int* __restrict__ cursor,
                              int* __restrict__ src_sorted, int* __restrict__ eid_sorted, int E) {
  int i = blockIdx.x * blockDim.x + threadIdx.x;
  if (i < E) {
    int d = dst[i];
    int pos = row_start[d] + atomicAdd(&cursor[d], 1);
    src_sorted[pos] = src[i];
    eid_sorted[pos] = i;
  }
}

// ---------------- weight prep: f32 -> f16, transposed ----------------
__global__ void transpose_w_f16(const float* __restrict__ W, __half* __restrict__ Wt, int K, int Nc) {
  int n = blockIdx.x * 16 + (threadIdx.x & 15);
  int k = blockIdx.y * 16 + (threadIdx.x >> 4);
  if (n < Nc && k < K) Wt[(size_t)n * K + k] = __float2half(W[(size_t)k * Nc + n]);
}

// ---------------- edge-coefficient vectors: wv[k][d], k=0..8 ----------------
__global__ void wvec_kernel(const float* __restrict__ We0, const float* __restrict__ ae0w,
                            const float* __restrict__ We1, const float* __restrict__ ae1w,
                            const float* __restrict__ We2, const float* __restrict__ ae2w,
                            float* __restrict__ wv) {
  int t = threadIdx.x;
  if (t < 144) {
    int k = t >> 4, d = t & 15;
    const float* We; const float* aev; int h; int HC;
    if (k < 4)      { We = We0; aev = ae0w; h = k;     HC = 256; }
    else if (k < 8) { We = We1; aev = ae1w; h = k - 4; HC = 256; }
    else            { We = We2; aev = ae2w; h = 0;     HC = 64; }
    float sum = 0.f;
#pragma unroll
    for (int c = 0; c < 64; ++c) sum += We[(size_t)d * HC + h * 64 + c] * aev[h * 64 + c];
    wv[k * 16 + d] = sum;
  }
}

// per-edge attention coefficients for all 3 layers, stored in CSR-sorted order
// random READ of ea (L2/L3-absorbed), coalesced writes
__global__ __launch_bounds__(256) void edge_ae(const float* __restrict__ ea,
                                               const int* __restrict__ eid_sorted,
                                               const float* __restrict__ wv,
                                               float* __restrict__ ae0, float* __restrict__ ae1,
                                               float* __restrict__ ae2, int E) {
  __shared__ float swv[144];
  if (threadIdx.x < 144) swv[threadIdx.x] = wv[threadIdx.x];
  __syncthreads();
  int p = blockIdx.x * blockDim.x + threadIdx.x;
  if (p >= E) return;
  int e = eid_sorted[p];
  const float4* er = (const float4*)(ea + (size_t)e * 16);
  float4 v0 = er[0], v1 = er[1], v2 = er[2], v3 = er[3];
  float ev[16] = {v0.x, v0.y, v0.z, v0.w, v1.x, v1.y, v1.z, v1.w,
                  v2.x, v2.y, v2.z, v2.w, v3.x, v3.y, v3.z, v3.w};
  float r[9];
#pragma unroll
  for (int k = 0; k < 9; ++k) {
    float s = 0.f;
#pragma unroll
    for (int d = 0; d < 16; ++d) s += ev[d] * swv[k * 16 + d];
    r[k] = s;
  }
  *(float4*)(ae0 + (size_t)p * 4) = make_float4(r[0], r[1], r[2], r[3]);
  *(float4*)(ae1 + (size_t)p * 4) = make_float4(r[4], r[5], r[6], r[7]);
  ae2[p] = r[8];
}

// ---------------- f16 MFMA GEMM: C[M,Nc] = A[M,K] @ Bt[Nc,K]^T ----------------
// AF32: A is f32 and converted to f16 during LDS staging (layer 0)
template <int BN, bool AF32>
__global__ __launch_bounds__(256) void gemm_f16mfma(const void* __restrict__ Av,
                                                    const __half* __restrict__ Bt,
                                                    __half* __restrict__ C, int M, int K, int Nc) {
  constexpr int BM = 128, BK = 64;
  constexpr int LDT = BK + 8;
  constexpr int WN = BN / 2;
  constexpr int NFN = WN / 16;
  __shared__ __half As[BM][LDT];
  __shared__ __half Bs[BN][LDT];
  const int tid = threadIdx.x;
  const int lane = tid & 63, wave = tid >> 6;
  const int wr = wave >> 1, wc = wave & 1;
  const int bm = blockIdx.x * BM;
  const int bn = blockIdx.y * BN;
  const int r15 = lane & 15, kgrp = lane >> 4;
  f32x4 acc[4][NFN] = {};
  for (int k0 = 0; k0 < K; k0 += BK) {
    if constexpr (AF32) {
      const float* A = (const float*)Av;
      // 128 rows x 16 float4-chunks (4 f32) = 2048 chunks / 256 threads
#pragma unroll
      for (int i = 0; i < 8; ++i) {
        int chunk = tid + i * 256;
        int row = chunk >> 4, kc = (chunk & 15) * 4;
        int grow = bm + row;
        float4 v = make_float4(0, 0, 0, 0);
        if (grow < M) v = *(const float4*)(A + (size_t)grow * K + k0 + kc);
        __half2 h01 = __floats2half2_rn(v.x, v.y);
        __half2 h23 = __floats2half2_rn(v.z, v.w);
        uint2 u;
        u.x = *(unsigned*)&h01;
        u.y = *(unsigned*)&h23;
        *(uint2*)&As[row][kc] = u;
      }
    } else {
      const __half* A = (const __half*)Av;
#pragma unroll
      for (int i = 0; i < 4; ++i) {
        int chunk = tid + i * 256;
        int row = chunk >> 3, kc = (chunk & 7) * 8;
        int grow = bm + row;
        float4 v = make_float4(0, 0, 0, 0);
        if (grow < M) v = *(const float4*)(A + (size_t)grow * K + k0 + kc);
        *(float4*)&As[row][kc] = v;
      }
    }
#pragma unroll
    for (int i = 0; i < BN / 32; ++i) {
      int chunk = tid + i * 256;
      int row = chunk >> 3, kc = (chunk & 7) * 8;
      *(float4*)&Bs[row][kc] = *(const float4*)(Bt + (size_t)(bn + row) * K + k0 + kc);
    }
    __syncthreads();
#pragma unroll
    for (int kk = 0; kk < BK; kk += 32) {
      f16x8 af[4], bf[NFN];
#pragma unroll
      for (int mi = 0; mi < 4; ++mi)
        af[mi] = *(const f16x8*)&As[wr * 64 + mi * 16 + r15][kk + kgrp * 8];
#pragma unroll
      for (int ni = 0; ni < NFN; ++ni)
        bf[ni] = *(const f16x8*)&Bs[wc * WN + ni * 16 + r15][kk + kgrp * 8];
#pragma unroll
      for (int mi = 0; mi < 4; ++mi)
#pragma unroll
        for (int ni = 0; ni < NFN; ++ni)
          acc[mi][ni] = __builtin_amdgcn_mfma_f32_16x16x32_f16(af[mi], bf[ni], acc[mi][ni], 0, 0, 0);
    }
    __syncthreads();
  }
#pragma unroll
  for (int mi = 0; mi < 4; ++mi) {
#pragma unroll
    for (int r = 0; r < 4; ++r) {
      int grow = bm + wr * 64 + mi * 16 + kgrp * 4 + r;
      if (grow < M) {
#pragma unroll
        for (int ni = 0; ni < NFN; ++ni) {
          int gcol = bn + wc * WN + ni * 16 + r15;
          C[(size_t)grow * Nc + gcol] = __float2half(acc[mi][ni][r]);
        }
      }
    }
  }
}

// ---------------- per-node a_src/a_dst dots (fp16 xp) ----------------
__global__ __launch_bounds__(256) void asad4(const __half* __restrict__ xp,
                                             const float* __restrict__ as_w,
                                             const float* __restrict__ ad_w,
                                             float* __restrict__ asb, float* __restrict__ adb, int N) {
  int wave = threadIdx.x >> 6, lane = threadIdx.x & 63;
  int n = blockIdx.x * 4 + wave;
  if (n >= N) return;
  const __half* xr = xp + (size_t)n * 256;
  float s[4], d[4];
#pragma unroll
  for (int h = 0; h < 4; ++h) {
    float v = __half2float(xr[h * 64 + lane]);
    s[h] = v * as_w[h * 64 + lane];
    d[h] = v * ad_w[h * 64 + lane];
  }
#pragma unroll
  for (int h = 0; h < 4; ++h) { s[h] = wred_sum(s[h]); d[h] = wred_sum(d[h]); }
  if (lane == 0) {
#pragma unroll
    for (int h = 0; h < 4; ++h) { asb[(size_t)n * 4 + h] = s[h]; adb[(size_t)n * 4 + h] = d[h]; }
  }
}

__global__ __launch_bounds__(256) void asad1(const __half* __restrict__ xp,
                                             const float* __restrict__ as_w,
                                             const float* __restrict__ ad_w,
                                             float* __restrict__ asb, float* __restrict__ adb, int N) {
  int wave = threadIdx.x >> 6, lane = threadIdx.x & 63;
  int n = blockIdx.x * 4 + wave;
  if (n >= N) return;
  float v = __half2float(xp[(size_t)n * 64 + lane]);
  float s = wred_sum(v * as_w[lane]);
  float d = wred_sum(v * ad_w[lane]);
  if (lane == 0) { asb[n] = s; adb[n] = d; }
}

// ---------------- fused segment-softmax + aggregation, heads=4 C=64, fp16 in/out ----------------
__global__ __launch_bounds__(256) void agg_heads4(
    const __half* __restrict__ xp, const int* __restrict__ src_sorted,
    const int* __restrict__ row_start, const float* __restrict__ asb,
    const float* __restrict__ adb, const float* __restrict__ ae,
    const float* __restrict__ bias, __half* __restrict__ out, int N) {
  __shared__ float sw[4][256];
  __shared__ int ssrc[4][64];
  int wave = threadIdx.x >> 6, lane = threadIdx.x & 63;
  int n = blockIdx.x * 4 + wave;
  if (n >= N) return;
  int beg = row_start[n], end = row_start[n + 1];
  int deg = end - beg;
  int hsel = lane >> 4;
  float4 adn = *(const float4*)(adb + (size_t)n * 4);
  float4 asn = *(const float4*)(asb + (size_t)n * 4);
  float invd = 1.f / fmaxf((float)deg, 1.f);
  f32x2 acc01 = {0.f, 0.f}, acc23 = {0.f, 0.f};
  float den0 = 0, den1 = 0, den2 = 0, den3 = 0;
  float m0, m1, m2, m3, al0, al1, al2, al3;
  const size_t loff = (size_t)(lane << 2);

  if (deg <= 64) {
    int j = beg + lane;
    bool act = j < end;
    int s = 0;
    float4 asv = make_float4(0, 0, 0, 0), aev = make_float4(0, 0, 0, 0);
    if (act) {
      s = src_sorted[j];
      asv = *(const float4*)(asb + (size_t)s * 4);
      aev = *(const float4*)(ae + (size_t)j * 4);
    }
    float l0 = act ? lrelu(asv.x + adn.x + aev.x) : -1e30f;
    float l1 = act ? lrelu(asv.y + adn.y + aev.y) : -1e30f;
    float l2 = act ? lrelu(asv.z + adn.z + aev.z) : -1e30f;
    float l3 = act ? lrelu(asv.w + adn.w + aev.w) : -1e30f;
    m0 = wred_max(l0); m1 = wred_max(l1); m2 = wred_max(l2); m3 = wred_max(l3);
    float aes0 = wred_sum(aev.x), aes1 = wred_sum(aev.y), aes2 = wred_sum(aev.z), aes3 = wred_sum(aev.w);
    al0 = lrelu(asn.x + adn.x + aes0 * invd);
    al1 = lrelu(asn.y + adn.y + aes1 * invd);
    al2 = lrelu(asn.z + adn.z + aes2 * invd);
    al3 = lrelu(asn.w + adn.w + aes3 * invd);
    m0 = fmaxf(m0, al0); m1 = fmaxf(m1, al1); m2 = fmaxf(m2, al2); m3 = fmaxf(m3, al3);
    float ex0 = act ? __expf(l0 - m0) : 0.f;
    float ex1 = act ? __expf(l1 - m1) : 0.f;
    float ex2 = act ? __expf(l2 - m2) : 0.f;
    float ex3 = act ? __expf(l3 - m3) : 0.f;
    den0 = wred_sum(ex0); den1 = wred_sum(ex1); den2 = wred_sum(ex2); den3 = wred_sum(ex3);
    *(float4*)&sw[wave][lane << 2] = make_float4(ex0, ex1, ex2, ex3);
    ssrc[wave][lane] = s;
    asm volatile("" ::: "memory");
    int cnt = deg;
    uint2 B[8];
#pragma unroll
    for (int q = 0; q < 8; ++q) {
      int ns = ssrc[wave][q & 63];
      B[q] = *(const uint2*)(xp + ((size_t)ns << 8) + loff);
    }
    for (int t = 0; t < cnt; t += 8) {
#pragma unroll
      for (int q = 0; q < 8; ++q) {
        float w = sw[wave][((t + q) << 2) + hsel];
        float2 fA = __half22float2(*(__half2*)&B[q].x);
        float2 fB = __half22float2(*(__half2*)&B[q].y);
        f32x2 w2 = {w, w};
        acc01 = __builtin_elementwise_fma((f32x2){fA.x, fA.y}, w2, acc01);
        acc23 = __builtin_elementwise_fma((f32x2){fB.x, fB.y}, w2, acc23);
        int ns = ssrc[wave][(t + q + 8) & 63];
        B[q] = *(const uint2*)(xp + ((size_t)ns << 8) + loff);
      }
    }
  } else {
    m0 = m1 = m2 = m3 = -1e30f;
    float aes0 = 0, aes1 = 0, aes2 = 0, aes3 = 0;
    for (int base = beg; base < end; base += 64) {
      int j = base + lane;
      if (j < end) {
        int s = src_sorted[j];
        float4 asv = *(const float4*)(asb + (size_t)s * 4);
        float4 aev = *(const float4*)(ae + (size_t)j * 4);
        aes0 += aev.x; aes1 += aev.y; aes2 += aev.z; aes3 += aev.w;
        m0 = fmaxf(m0, lrelu(asv.x + adn.x + aev.x));
        m1 = fmaxf(m1, lrelu(asv.y + adn.y + aev.y));
        m2 = fmaxf(m2, lrelu(asv.z + adn.z + aev.z));
        m3 = fmaxf(m3, lrelu(asv.w + adn.w + aev.w));
      }
    }
    m0 = wred_max(m0); m1 = wred_max(m1); m2 = wred_max(m2); m3 = wred_max(m3);
    aes0 = wred_sum(aes0); aes1 = wred_sum(aes1); aes2 = wred_sum(aes2); aes3 = wred_sum(aes3);
    al0 = lrelu(asn.x + adn.x + aes0 * invd);
    al1 = lrelu(asn.y + adn.y + aes1 * invd);
    al2 = lrelu(asn.z + adn.z + aes2 * invd);
    al3 = lrelu(asn.w + adn.w + aes3 * invd);
    m0 = fmaxf(m0, al0); m1 = fmaxf(m1, al1); m2 = fmaxf(m2, al2); m3 = fmaxf(m3, al3);
    for (int base = beg; base < end; base += 64) {
      int j = base + lane;
      float ex0 = 0, ex1 = 0, ex2 = 0, ex3 = 0;
      int s = 0;
      if (j < end) {
        s = src_sorted[j];
        float4 asv = *(const float4*)(asb + (size_t)s * 4);
        float4 aev = *(const float4*)(ae + (size_t)j * 4);
        ex0 = __expf(lrelu(asv.x + adn.x + aev.x) - m0);
        ex1 = __expf(lrelu(asv.y + adn.y + aev.y) - m1);
        ex2 = __expf(lrelu(asv.z + adn.z + aev.z) - m2);
        ex3 = __expf(lrelu(asv.w + adn.w + aev.w) - m3);
        den0 += ex0; den1 += ex1; den2 += ex2; den3 += ex3;
      }
      int cnt = min(64, end - base);
      for (int t = 0; t < cnt; ++t) {
        int sj = __shfl(s, t);
        float w0 = __shfl(ex0, t), w1 = __shfl(ex1, t), w2 = __shfl(ex2, t), w3 = __shfl(ex3, t);
        float w = hsel == 0 ? w0 : (hsel == 1 ? w1 : (hsel == 2 ? w2 : w3));
        uint2 u = *(const uint2*)(xp + ((size_t)sj << 8) + loff);
        float2 fA = __half22float2(*(__half2*)&u.x);
        float2 fB = __half22float2(*(__half2*)&u.y);
        f32x2 w2v = {w, w};
        acc01 = __builtin_elementwise_fma((f32x2){fA.x, fA.y}, w2v, acc01);
        acc23 = __builtin_elementwise_fma((f32x2){fB.x, fB.y}, w2v, acc23);
      }
    }
    den0 = wred_sum(den0); den1 = wred_sum(den1); den2 = wred_sum(den2); den3 = wred_sum(den3);
  }

  float exl0 = __expf(al0 - m0), exl1 = __expf(al1 - m1), exl2 = __expf(al2 - m2), exl3 = __expf(al3 - m3);
  den0 += exl0; den1 += exl1; den2 += exl2; den3 += exl3;
  float exh = hsel == 0 ? exl0 : (hsel == 1 ? exl1 : (hsel == 2 ? exl2 : exl3));
  {
    uint2 u = *(const uint2*)(xp + ((size_t)n << 8) + loff);
    float2 fA = __half22float2(*(__half2*)&u.x);
    float2 fB = __half22float2(*(__half2*)&u.y);
    f32x2 w2v = {exh, exh};
    acc01 = __builtin_elementwise_fma((f32x2){fA.x, fA.y}, w2v, acc01);
    acc23 = __builtin_elementwise_fma((f32x2){fB.x, fB.y}, w2v, acc23);
  }
  float denh = hsel == 0 ? den0 : (hsel == 1 ? den1 : (hsel == 2 ? den2 : den3));
  float rden = 1.f / (denh + 1e-16f);
  float4 bv = *(const float4*)(bias + (lane << 2));
  __half2 o01 = __floats2half2_rn(fmaxf(acc01[0] * rden + bv.x, 0.f), fmaxf(acc01[1] * rden + bv.y, 0.f));
  __half2 o23 = __floats2half2_rn(fmaxf(acc23[0] * rden + bv.z, 0.f), fmaxf(acc23[1] * rden + bv.w, 0.f));
  uint2 u;
  u.x = *(unsigned*)&o01;
  u.y = *(unsigned*)&o23;
  *(uint2*)(out + (size_t)n * 256 + (lane << 2)) = u;
}

// ---------------- layer2 (heads=1) + final linear + sigmoid, fused ----------------
__global__ __launch_bounds__(256) void agg1_final(
    const __half* __restrict__ xp, const int* __restrict__ src_sorted,
    const int* __restrict__ row_start, const float* __restrict__ asb,
    const float* __restrict__ adb, const float* __restrict__ ae,
    const float* __restrict__ b2, const float* __restrict__ lin_w,
    const float* __restrict__ lin_b, float* __restrict__ out, int N) {
  __shared__ float sw1[4][64];
  __shared__ int ssrc1[4][64];
  int wave = threadIdx.x >> 6, lane = threadIdx.x & 63;
  int n = blockIdx.x * 4 + wave;
  if (n >= N) return;
  int beg = row_start[n], end = row_start[n + 1];
  int deg = end - beg;
  float adn = adb[n], asn = asb[n];
  float invd = 1.f / fmaxf((float)deg, 1.f);
  float m, al, acc = 0, den = 0;

  if (deg <= 64) {
    int j = beg + lane;
    bool act = j < end;
    int s = 0;
    float aev = 0, asvs = 0;
    if (act) { s = src_sorted[j]; aev = ae[j]; asvs = asb[s]; }
    float l = act ? lrelu(asvs + adn + aev) : -1e30f;
    m = wred_max(l);
    float aes = wred_sum(aev);
    al = lrelu(asn + adn + aes * invd);
    m = fmaxf(m, al);
    float ex = act ? __expf(l - m) : 0.f;
    den = wred_sum(ex);
    sw1[wave][lane] = ex;
    ssrc1[wave][lane] = s;
    asm volatile("" ::: "memory");
    int cnt = deg;
    __half H[8];
#pragma unroll
    for (int q = 0; q < 8; ++q) {
      int ns = ssrc1[wave][q & 63];
      H[q] = xp[((size_t)ns << 6) + lane];
    }
    for (int t = 0; t < cnt; t += 8) {
#pragma unroll
      for (int q = 0; q < 8; ++q) {
        float w = sw1[wave][t + q];
        acc = fmaf(w, __half2float(H[q]), acc);
        int ns = ssrc1[wave][(t + q + 8) & 63];
        H[q] = xp[((size_t)ns << 6) + lane];
      }
    }
  } else {
    m = -1e30f;
    float aes = 0;
    for (int base = beg; base < end; base += 64) {
      int j = base + lane;
      if (j < end) {
        int s = src_sorted[j];
        float aev = ae[j];
        aes += aev;
        m = fmaxf(m, lrelu(asb[s] + adn + aev));
      }
    }
    m = wred_max(m);
    aes = wred_sum(aes);
    al = lrelu(asn + adn + aes * invd);
    m = fmaxf(m, al);
    for (int base = beg; base < end; base += 64) {
      int j = base + lane;
      float ex = 0;
      int s = 0;
      if (j < end) {
        s = src_sorted[j];
        ex = __expf(lrelu(asb[s] + adn + ae[j]) - m);
        den += ex;
      }
      int cnt = min(64, end - base);
      for (int t = 0; t < cnt; ++t) {
        int sj = __shfl(s, t);
        float w = __shfl(ex, t);
        acc = fmaf(w, __half2float(xp[((size_t)sj << 6) + lane]), acc);
      }
    }
    den = wred_sum(den);
  }

  float exl = __expf(al - m);
  den += exl;
  acc = fmaf(exl, __half2float(xp[((size_t)n << 6) + lane]), acc);
  float h = fmaxf(acc / (den + 1e-16f) + b2[lane], 0.f);
  float p = wred_sum(h * lin_w[lane]);
  if (lane == 0) out[n] = 1.f / (1.f + __expf(-(p + lin_b[0])));
}

// ---------------- host glue ----------------
extern "C" void kernel_launch(void* const* d_in, const int* in_sizes, int n_in,
                              void* d_out, int out_size, void* d_ws, size_t ws_size,
                              hipStream_t stream) {
  const float* x    = (const float*)d_in[0];
  const int*   ei   = (const int*)d_in[1];
  const float* ea   = (const float*)d_in[2];
  const float* W0   = (const float*)d_in[3];
  const float* as0w = (const float*)d_in[4];
  const float* ad0w = (const float*)d_in[5];
  const float* We0  = (const float*)d_in[6];
  const float* ae0w = (const float*)d_in[7];
  const float* b0   = (const float*)d_in[8];
  const float* W1   = (const float*)d_in[9];
  const float* as1w = (const float*)d_in[10];
  const float* ad1w = (const float*)d_in[11];
  const float* We1  = (const float*)d_in[12];
  const float* ae1w = (const float*)d_in[13];
  const float* b1   = (const float*)d_in[14];
  const float* W2   = (const float*)d_in[15];
  const float* as2w = (const float*)d_in[16];
  const float* ad2w = (const float*)d_in[17];
  const float* We2  = (const float*)d_in[18];
  const float* ae2w = (const float*)d_in[19];
  const float* b2   = (const float*)d_in[20];
  const float* linw = (const float*)d_in[21];
  const float* linb = (const float*)d_in[22];

  const int N = in_sizes[0] / 128;
  const int E = in_sizes[1] / 2;
  const int* src = ei;
  const int* dst = ei + E;

  char* p = (char*)d_ws;
  auto alloc = [&](size_t bytes) {
    char* r = p;
    p += (bytes + 255) & ~size_t(255);
    return r;
  };
  __half* bufAh      = (__half*)alloc((size_t)N * 256 * 2);
  __half* xph        = (__half*)alloc((size_t)N * 256 * 2);
  __half* W0t        = (__half*)alloc((size_t)256 * 128 * 2);
  __half* W1t        = (__half*)alloc((size_t)256 * 256 * 2);
  __half* W2t        = (__half*)alloc((size_t)64 * 256 * 2);
  float*  asb        = (float*)alloc((size_t)N * 4 * 4);
  float*  adb        = (float*)alloc((size_t)N * 4 * 4);
  int*    src_sorted = (int*)alloc((size_t)E * 4);
  int*    eid_sorted = (int*)alloc((size_t)E * 4);
  float*  ae0s       = (float*)alloc((size_t)E * 4 * 4);
  float*  ae1s       = (float*)alloc((size_t)E * 4 * 4);
  float*  ae2s       = (float*)alloc((size_t)E * 4);
  int*    deg        = (int*)alloc((size_t)N * 4);
  int*    row_start  = (int*)alloc((size_t)(N + 1) * 4);
  int*    cursor     = (int*)alloc((size_t)N * 4);
  int*    bsum       = (int*)alloc((size_t)256 * 4);
  int*    boff       = (int*)alloc((size_t)256 * 4);
  float*  wv         = (float*)alloc(144 * 4);

  int nb = (N + 255) / 256;
  int eb = (E + 255) / 256;
  zero_int2<<<nb, 256, 0, stream>>>(deg, cursor, N);
  count_deg<<<eb, 256, 0, stream>>>(dst, deg, E);
  scan_part<<<nb, 256, 0, stream>>>(deg, bsum, N);
  scan_bsum<<<1, 256, 0, stream>>>(bsum, boff, nb);
  scan_final<<<nb, 256, 0, stream>>>(deg, boff, row_start, N);
  scatter_edges<<<eb, 256, 0, stream>>>(src, dst, row_start, cursor, src_sorted, eid_sorted, E);
  wvec_kernel<<<1, 160, 0, stream>>>(We0, ae0w, We1, ae1w, We2, ae2w, wv);
  edge_ae<<<eb, 256, 0, stream>>>(ea, eid_sorted, wv, ae0s, ae1s, ae2s, E);

  transpose_w_f16<<<dim3(16, 8), 256, 0, stream>>>(W0, W0t, 128, 256);
  transpose_w_f16<<<dim3(16, 16), 256, 0, stream>>>(W1, W1t, 256, 256);
  transpose_w_f16<<<dim3(4, 16), 256, 0, stream>>>(W2, W2t, 256, 64);

  int gm = (N + 127) / 128;
  int nwb = (N + 3) / 4;
  // layer 0 (A = x in f32, converted during staging)
  gemm_f16mfma<128, true><<<dim3(gm, 2), 256, 0, stream>>>(x, W0t, xph, N, 128, 256);
  asad4<<<nwb, 256, 0, stream>>>(xph, as0w, ad0w, asb, adb, N);
  agg_heads4<<<nwb, 256, 0, stream>>>(xph, src_sorted, row_start, asb, adb, ae0s, b0, bufAh, N);
  // layer 1
  gemm_f16mfma<128, false><<<dim3(gm, 2), 256, 0, stream>>>(bufAh, W1t, xph, N, 256, 256);
  asad4<<<nwb, 256, 0, stream>>>(xph, as1w, ad1w, asb, adb, N);
  agg_heads4<<<nwb, 256, 0, stream>>>(xph, src_sorted, row_start, asb, adb, ae1s, b1, bufAh, N);
  // layer 2 + final linear + sigmoid
  gemm_f16mfma<64, false><<<dim3(gm, 1), 256, 0, stream>>>(bufAh, W2t, xph, N, 256, 64);
  asad1<<<nwb, 256, 0, stream>>>(xph, as2w, ad2w, asb, adb, N);
  agg1_final<<<nwb, 256, 0, stream>>>(xph, src_sorted, row_start, asb, adb, ae2s, b2, linw, linb,
                                      (float*)d_out, N);
}

// Round 8
// 398.389 us; speedup vs baseline: 1.0882x; 1.0882x over previous
//
#include <hip/hip_runtime.h>
#include <hip/hip_fp16.h>

using f16x8 = __attribute__((ext_vector_type(8))) _Float16;
using f32x4 = __attribute__((ext_vector_type(4))) float;

// ---------------- wave helpers (wave = 64 lanes on CDNA) ----------------
static __device__ __forceinline__ float wred_max(float v) {
#pragma unroll
  for (int o = 32; o > 0; o >>= 1) v = fmaxf(v, __shfl_xor(v, o));
  return v;
}
static __device__ __forceinline__ float wred_sum(float v) {
#pragma unroll
  for (int o = 32; o > 0; o >>= 1) v += __shfl_xor(v, o);
  return v;
}
static __device__ __forceinline__ float lrelu(float x) { return x > 0.f ? x : 0.2f * x; }

// ---------------- preprocessing ----------------
__global__ void zero_all(int* __restrict__ deg, int* __restrict__ cursor,
                         float* __restrict__ asb0, float* __restrict__ adb0,
                         float* __restrict__ asb1, float* __restrict__ adb1,
                         float* __restrict__ asb2, float* __restrict__ adb2, int n) {
  int i = blockIdx.x * blockDim.x + threadIdx.x;
  if (i < n) {
    deg[i] = 0;
    cursor[i] = 0;
    asb2[i] = 0.f;
    adb2[i] = 0.f;
    float4 z = make_float4(0, 0, 0, 0);
    *(float4*)(asb0 + (size_t)i * 4) = z;
    *(float4*)(adb0 + (size_t)i * 4) = z;
    *(float4*)(asb1 + (size_t)i * 4) = z;
    *(float4*)(adb1 + (size_t)i * 4) = z;
  }
}

__global__ void count_deg(const int* __restrict__ dst, int* __restrict__ deg, int E) {
  int i = blockIdx.x * blockDim.x + threadIdx.x;
  if (i < E) atomicAdd(&deg[dst[i]], 1);
}

// ---------------- multi-block exclusive scan (3 kernels) ----------------
__global__ __launch_bounds__(256) void scan_part(const int* __restrict__ deg,
                                                 int* __restrict__ bsum, int n) {
  __shared__ int sd[256];
  int tid = threadIdx.x;
  int i = blockIdx.x * 256 + tid;
  sd[tid] = (i < n) ? deg[i] : 0;
  __syncthreads();
#pragma unroll
  for (int d = 128; d > 0; d >>= 1) {
    if (tid < d) sd[tid] += sd[tid + d];
    __syncthreads();
  }
  if (tid == 0) bsum[blockIdx.x] = sd[0];
}

__global__ __launch_bounds__(256) void scan_bsum(const int* __restrict__ bsum,
                                                 int* __restrict__ boff, int nb) {
  __shared__ int sd[256];
  int tid = threadIdx.x;
  int v = (tid < nb) ? bsum[tid] : 0;
  sd[tid] = v;
  __syncthreads();
#pragma unroll
  for (int d = 1; d < 256; d <<= 1) {
    int t = (tid >= d) ? sd[tid - d] : 0;
    __syncthreads();
    sd[tid] += t;
    __syncthreads();
  }
  if (tid < nb) boff[tid] = sd[tid] - v;  // exclusive
}

__global__ __launch_bounds__(256) void scan_final(const int* __restrict__ deg,
                                                  const int* __restrict__ boff,
                                                  int* __restrict__ row_start, int n) {
  __shared__ int sd[256];
  int tid = threadIdx.x;
  int i = blockIdx.x * 256 + tid;
  int v = (i < n) ? deg[i] : 0;
  sd[tid] = v;
  __syncthreads();
#pragma unroll
  for (int d = 1; d < 256; d <<= 1) {
    int t = (tid >= d) ? sd[tid - d] : 0;
    __syncthreads();
    sd[tid] += t;
    __syncthreads();
  }
  int incl = sd[tid];
  int base = boff[blockIdx.x];
  if (i < n) row_start[i] = base + incl - v;
  if (i == n - 1) row_start[n] = base + incl;
}

__global__ void scatter_edges(const int* __restrict__ src, const int* __restrict__ dst,
                              const int* __restrict__ row_start, int* __restrict__ cursor,
                              int* __restrict__ src_sorted, int* __restrict__ eid_sorted, int E) {
  int i = blockIdx.x * blockDim.x + threadIdx.x;
  if (i < E) {
    int d = dst[i];
    int pos = row_start[d] + atomicAdd(&cursor[d], 1);
    src_sorted[pos] = src[i];
    eid_sorted[pos] = i;
  }
}

// ---------------- weight prep: f32 -> f16, transposed ----------------
__global__ void transpose_w_f16(const float* __restrict__ W, __half* __restrict__ Wt, int K, int Nc) {
  int n = blockIdx.x * 16 + (threadIdx.x & 15);
  int k = blockIdx.y * 16 + (threadIdx.x >> 4);
  if (n < Nc && k < K) Wt[(size_t)n * K + k] = __float2half(W[(size_t)k * Nc + n]);
}

// ---------------- edge-coefficient vectors: wv[k][d], k=0..8 ----------------
__global__ void wvec_kernel(const float* __restrict__ We0, const float* __restrict__ ae0w,
                            const float* __restrict__ We1, const float* __restrict__ ae1w,
                            const float* __restrict__ We2, const float* __restrict__ ae2w,
                            float* __restrict__ wv) {
  int t = threadIdx.x;
  if (t < 144) {
    int k = t >> 4, d = t & 15;
    const float* We; const float* aev; int h; int HC;
    if (k < 4)      { We = We0; aev = ae0w; h = k;     HC = 256; }
    else if (k < 8) { We = We1; aev = ae1w; h = k - 4; HC = 256; }
    else            { We = We2; aev = ae2w; h = 0;     HC = 64; }
    float sum = 0.f;
#pragma unroll
    for (int c = 0; c < 64; ++c) sum += We[(size_t)d * HC + h * 64 + c] * aev[h * 64 + c];
    wv[k * 16 + d] = sum;
  }
}

// per-edge attention coefficients, CSR-sorted order (random READ, coalesced writes)
__global__ __launch_bounds__(256) void edge_ae(const float* __restrict__ ea,
                                               const int* __restrict__ eid_sorted,
                                               const float* __restrict__ wv,
                                               float* __restrict__ ae0, float* __restrict__ ae1,
                                               float* __restrict__ ae2, int E) {
  __shared__ float swv[144];
  if (threadIdx.x < 144) swv[threadIdx.x] = wv[threadIdx.x];
  __syncthreads();
  int p = blockIdx.x * blockDim.x + threadIdx.x;
  if (p >= E) return;
  int e = eid_sorted[p];
  const float4* er = (const float4*)(ea + (size_t)e * 16);
  float4 v0 = er[0], v1 = er[1], v2 = er[2], v3 = er[3];
  float ev[16] = {v0.x, v0.y, v0.z, v0.w, v1.x, v1.y, v1.z, v1.w,
                  v2.x, v2.y, v2.z, v2.w, v3.x, v3.y, v3.z, v3.w};
  float r[9];
#pragma unroll
  for (int k = 0; k < 9; ++k) {
    float s = 0.f;
#pragma unroll
    for (int d = 0; d < 16; ++d) s += ev[d] * swv[k * 16 + d];
    r[k] = s;
  }
  *(float4*)(ae0 + (size_t)p * 4) = make_float4(r[0], r[1], r[2], r[3]);
  *(float4*)(ae1 + (size_t)p * 4) = make_float4(r[4], r[5], r[6], r[7]);
  ae2[p] = r[8];
}

// ---------------- f16 MFMA GEMM + fused a_src/a_dst dots in epilogue ----------------
// AF32: A is f32, converted during LDS staging. HS: head stride of asb/adb (4 or 1).
// Each wave's 64 output cols = one head (BN=128) or head 0 (BN=64).
template <int BN, bool AF32, int HS>
__global__ __launch_bounds__(256) void gemm_f16mfma(const void* __restrict__ Av,
                                                    const __half* __restrict__ Bt,
                                                    __half* __restrict__ C,
                                                    const float* __restrict__ as_w,
                                                    const float* __restrict__ ad_w,
                                                    float* __restrict__ asb,
                                                    float* __restrict__ adb,
                                                    int M, int K, int Nc) {
  constexpr int BM = 128, BK = 64;
  constexpr int LDT = BK + 8;
  constexpr int WN = BN / 2;
  constexpr int NFN = WN / 16;
  __shared__ __half As[BM][LDT];
  __shared__ __half Bs[BN][LDT];
  const int tid = threadIdx.x;
  const int lane = tid & 63, wave = tid >> 6;
  const int wr = wave >> 1, wc = wave & 1;
  const int bm = blockIdx.x * BM;
  const int bn = blockIdx.y * BN;
  const int r15 = lane & 15, kgrp = lane >> 4;
  f32x4 acc[4][NFN] = {};
  for (int k0 = 0; k0 < K; k0 += BK) {
    if constexpr (AF32) {
      const float* A = (const float*)Av;
#pragma unroll
      for (int i = 0; i < 8; ++i) {
        int chunk = tid + i * 256;
        int row = chunk >> 4, kc = (chunk & 15) * 4;
        int grow = bm + row;
        float4 v = make_float4(0, 0, 0, 0);
        if (grow < M) v = *(const float4*)(A + (size_t)grow * K + k0 + kc);
        __half2 h01 = __floats2half2_rn(v.x, v.y);
        __half2 h23 = __floats2half2_rn(v.z, v.w);
        uint2 u;
        u.x = *(unsigned*)&h01;
        u.y = *(unsigned*)&h23;
        *(uint2*)&As[row][kc] = u;
      }
    } else {
      const __half* A = (const __half*)Av;
#pragma unroll
      for (int i = 0; i < 4; ++i) {
        int chunk = tid + i * 256;
        int row = chunk >> 3, kc = (chunk & 7) * 8;
        int grow = bm + row;
        float4 v = make_float4(0, 0, 0, 0);
        if (grow < M) v = *(const float4*)(A + (size_t)grow * K + k0 + kc);
        *(float4*)&As[row][kc] = v;
      }
    }
#pragma unroll
    for (int i = 0; i < BN / 32; ++i) {
      int chunk = tid + i * 256;
      int row = chunk >> 3, kc = (chunk & 7) * 8;
      *(float4*)&Bs[row][kc] = *(const float4*)(Bt + (size_t)(bn + row) * K + k0 + kc);
    }
    __syncthreads();
#pragma unroll
    for (int kk = 0; kk < BK; kk += 32) {
      f16x8 af[4], bf[NFN];
#pragma unroll
      for (int mi = 0; mi < 4; ++mi)
        af[mi] = *(const f16x8*)&As[wr * 64 + mi * 16 + r15][kk + kgrp * 8];
#pragma unroll
      for (int ni = 0; ni < NFN; ++ni)
        bf[ni] = *(const f16x8*)&Bs[wc * WN + ni * 16 + r15][kk + kgrp * 8];
#pragma unroll
      for (int mi = 0; mi < 4; ++mi)
#pragma unroll
        for (int ni = 0; ni < NFN; ++ni)
          acc[mi][ni] = __builtin_amdgcn_mfma_f32_16x16x32_f16(af[mi], bf[ni], acc[mi][ni], 0, 0, 0);
    }
    __syncthreads();
  }
  // preload attention weights for this thread's columns
  float asw[NFN], adw[NFN];
#pragma unroll
  for (int ni = 0; ni < NFN; ++ni) {
    int gcol = bn + wc * WN + ni * 16 + r15;
    asw[ni] = as_w[gcol];
    adw[ni] = ad_w[gcol];
  }
  const int hidx = (bn + wc * WN) >> 6;
#pragma unroll
  for (int mi = 0; mi < 4; ++mi) {
#pragma unroll
    for (int r = 0; r < 4; ++r) {
      int grow = bm + wr * 64 + mi * 16 + kgrp * 4 + r;
      bool valid = grow < M;
      float sdot = 0.f, ddot = 0.f;
#pragma unroll
      for (int ni = 0; ni < NFN; ++ni) {
        float v = acc[mi][ni][r];
        if (valid) {
          int gcol = bn + wc * WN + ni * 16 + r15;
          C[(size_t)grow * Nc + gcol] = __float2half(v);
        }
        sdot = fmaf(v, asw[ni], sdot);
        ddot = fmaf(v, adw[ni], ddot);
      }
#pragma unroll
      for (int o = 8; o >= 1; o >>= 1) {
        sdot += __shfl_xor(sdot, o);
        ddot += __shfl_xor(ddot, o);
      }
      if (valid && r15 == 0) {
        atomicAdd(&asb[(size_t)grow * HS + hidx], sdot);
        atomicAdd(&adb[(size_t)grow * HS + hidx], ddot);
      }
    }
  }
}

// ---------------- fused segment-softmax + aggregation, heads=4 C=64, fp16 in/out ----------------
__global__ __launch_bounds__(256) void agg_heads4(
    const __half* __restrict__ xp, const int* __restrict__ src_sorted,
    const int* __restrict__ row_start, const float* __restrict__ asb,
    const float* __restrict__ adb, const float* __restrict__ ae,
    const float* __restrict__ bias, __half* __restrict__ out, int N) {
  __shared__ float sw[4][256];
  __shared__ int ssrc[4][64];
  int wave = threadIdx.x >> 6, lane = threadIdx.x & 63;
  int n = blockIdx.x * 4 + wave;
  if (n >= N) return;
  int beg = row_start[n], end = row_start[n + 1];
  int deg = end - beg;
  int hsel = lane >> 4;
  float4 adn = *(const float4*)(adb + (size_t)n * 4);
  float4 asn = *(const float4*)(asb + (size_t)n * 4);
  float invd = 1.f / fmaxf((float)deg, 1.f);
  float acc0 = 0, acc1 = 0, acc2 = 0, acc3 = 0;
  float den0 = 0, den1 = 0, den2 = 0, den3 = 0;
  float m0, m1, m2, m3, al0, al1, al2, al3;
  const size_t loff = (size_t)(lane << 2);

  if (deg <= 64) {
    int j = beg + lane;
    bool act = j < end;
    int s = 0;
    float4 asv = make_float4(0, 0, 0, 0), aev = make_float4(0, 0, 0, 0);
    if (act) {
      s = src_sorted[j];
      asv = *(const float4*)(asb + (size_t)s * 4);
      aev = *(const float4*)(ae + (size_t)j * 4);
    }
    float l0 = act ? lrelu(asv.x + adn.x + aev.x) : -1e30f;
    float l1 = act ? lrelu(asv.y + adn.y + aev.y) : -1e30f;
    float l2 = act ? lrelu(asv.z + adn.z + aev.z) : -1e30f;
    float l3 = act ? lrelu(asv.w + adn.w + aev.w) : -1e30f;
    m0 = wred_max(l0); m1 = wred_max(l1); m2 = wred_max(l2); m3 = wred_max(l3);
    float aes0 = wred_sum(aev.x), aes1 = wred_sum(aev.y), aes2 = wred_sum(aev.z), aes3 = wred_sum(aev.w);
    al0 = lrelu(asn.x + adn.x + aes0 * invd);
    al1 = lrelu(asn.y + adn.y + aes1 * invd);
    al2 = lrelu(asn.z + adn.z + aes2 * invd);
    al3 = lrelu(asn.w + adn.w + aes3 * invd);
    m0 = fmaxf(m0, al0); m1 = fmaxf(m1, al1); m2 = fmaxf(m2, al2); m3 = fmaxf(m3, al3);
    float ex0 = act ? __expf(l0 - m0) : 0.f;
    float ex1 = act ? __expf(l1 - m1) : 0.f;
    float ex2 = act ? __expf(l2 - m2) : 0.f;
    float ex3 = act ? __expf(l3 - m3) : 0.f;
    den0 = wred_sum(ex0); den1 = wred_sum(ex1); den2 = wred_sum(ex2); den3 = wred_sum(ex3);
    *(float4*)&sw[wave][lane << 2] = make_float4(ex0, ex1, ex2, ex3);
    ssrc[wave][lane] = s;
    asm volatile("" ::: "memory");
    int cnt = deg;
    int sj0 = ssrc[wave][0], sj1 = ssrc[wave][1], sj2 = ssrc[wave][2], sj3 = ssrc[wave][3];
    uint2 B0 = *(const uint2*)(xp + ((size_t)sj0 << 8) + loff);
    uint2 B1 = *(const uint2*)(xp + ((size_t)sj1 << 8) + loff);
    uint2 B2 = *(const uint2*)(xp + ((size_t)sj2 << 8) + loff);
    uint2 B3 = *(const uint2*)(xp + ((size_t)sj3 << 8) + loff);
    for (int t = 0; t < cnt; t += 4) {
      {
        float w = sw[wave][((t + 0) << 2) + hsel];
        float2 fA = __half22float2(*(__half2*)&B0.x);
        float2 fB = __half22float2(*(__half2*)&B0.y);
        acc0 = fmaf(w, fA.x, acc0); acc1 = fmaf(w, fA.y, acc1);
        acc2 = fmaf(w, fB.x, acc2); acc3 = fmaf(w, fB.y, acc3);
        int ns = ssrc[wave][(t + 4) & 63];
        B0 = *(const uint2*)(xp + ((size_t)ns << 8) + loff);
      }
      {
        float w = sw[wave][((t + 1) << 2) + hsel];
        float2 fA = __half22float2(*(__half2*)&B1.x);
        float2 fB = __half22float2(*(__half2*)&B1.y);
        acc0 = fmaf(w, fA.x, acc0); acc1 = fmaf(w, fA.y, acc1);
        acc2 = fmaf(w, fB.x, acc2); acc3 = fmaf(w, fB.y, acc3);
        int ns = ssrc[wave][(t + 5) & 63];
        B1 = *(const uint2*)(xp + ((size_t)ns << 8) + loff);
      }
      {
        float w = sw[wave][((t + 2) << 2) + hsel];
        float2 fA = __half22float2(*(__half2*)&B2.x);
        float2 fB = __half22float2(*(__half2*)&B2.y);
        acc0 = fmaf(w, fA.x, acc0); acc1 = fmaf(w, fA.y, acc1);
        acc2 = fmaf(w, fB.x, acc2); acc3 = fmaf(w, fB.y, acc3);
        int ns = ssrc[wave][(t + 6) & 63];
        B2 = *(const uint2*)(xp + ((size_t)ns << 8) + loff);
      }
      {
        float w = sw[wave][((t + 3) << 2) + hsel];
        float2 fA = __half22float2(*(__half2*)&B3.x);
        float2 fB = __half22float2(*(__half2*)&B3.y);
        acc0 = fmaf(w, fA.x, acc0); acc1 = fmaf(w, fA.y, acc1);
        acc2 = fmaf(w, fB.x, acc2); acc3 = fmaf(w, fB.y, acc3);
        int ns = ssrc[wave][(t + 7) & 63];
        B3 = *(const uint2*)(xp + ((size_t)ns << 8) + loff);
      }
    }
  } else {
    m0 = m1 = m2 = m3 = -1e30f;
    float aes0 = 0, aes1 = 0, aes2 = 0, aes3 = 0;
    for (int base = beg; base < end; base += 64) {
      int j = base + lane;
      if (j < end) {
        int s = src_sorted[j];
        float4 asv = *(const float4*)(asb + (size_t)s * 4);
        float4 aev = *(const float4*)(ae + (size_t)j * 4);
        aes0 += aev.x; aes1 += aev.y; aes2 += aev.z; aes3 += aev.w;
        m0 = fmaxf(m0, lrelu(asv.x + adn.x + aev.x));
        m1 = fmaxf(m1, lrelu(asv.y + adn.y + aev.y));
        m2 = fmaxf(m2, lrelu(asv.z + adn.z + aev.z));
        m3 = fmaxf(m3, lrelu(asv.w + adn.w + aev.w));
      }
    }
    m0 = wred_max(m0); m1 = wred_max(m1); m2 = wred_max(m2); m3 = wred_max(m3);
    aes0 = wred_sum(aes0); aes1 = wred_sum(aes1); aes2 = wred_sum(aes2); aes3 = wred_sum(aes3);
    al0 = lrelu(asn.x + adn.x + aes0 * invd);
    al1 = lrelu(asn.y + adn.y + aes1 * invd);
    al2 = lrelu(asn.z + adn.z + aes2 * invd);
    al3 = lrelu(asn.w + adn.w + aes3 * invd);
    m0 = fmaxf(m0, al0); m1 = fmaxf(m1, al1); m2 = fmaxf(m2, al2); m3 = fmaxf(m3, al3);
    for (int base = beg; base < end; base += 64) {
      int j = base + lane;
      float ex0 = 0, ex1 = 0, ex2 = 0, ex3 = 0;
      int s = 0;
      if (j < end) {
        s = src_sorted[j];
        float4 asv = *(const float4*)(asb + (size_t)s * 4);
        float4 aev = *(const float4*)(ae + (size_t)j * 4);
        ex0 = __expf(lrelu(asv.x + adn.x + aev.x) - m0);
        ex1 = __expf(lrelu(asv.y + adn.y + aev.y) - m1);
        ex2 = __expf(lrelu(asv.z + adn.z + aev.z) - m2);
        ex3 = __expf(lrelu(asv.w + adn.w + aev.w) - m3);
        den0 += ex0; den1 += ex1; den2 += ex2; den3 += ex3;
      }
      int cnt = min(64, end - base);
      for (int t = 0; t < cnt; ++t) {
        int sj = __shfl(s, t);
        float w0 = __shfl(ex0, t), w1 = __shfl(ex1, t), w2 = __shfl(ex2, t), w3 = __shfl(ex3, t);
        float w = hsel == 0 ? w0 : (hsel == 1 ? w1 : (hsel == 2 ? w2 : w3));
        uint2 u = *(const uint2*)(xp + ((size_t)sj << 8) + loff);
        float2 fA = __half22float2(*(__half2*)&u.x);
        float2 fB = __half22float2(*(__half2*)&u.y);
        acc0 = fmaf(w, fA.x, acc0);
        acc1 = fmaf(w, fA.y, acc1);
        acc2 = fmaf(w, fB.x, acc2);
        acc3 = fmaf(w, fB.y, acc3);
      }
    }
    den0 = wred_sum(den0); den1 = wred_sum(den1); den2 = wred_sum(den2); den3 = wred_sum(den3);
  }

  float exl0 = __expf(al0 - m0), exl1 = __expf(al1 - m1), exl2 = __expf(al2 - m2), exl3 = __expf(al3 - m3);
  den0 += exl0; den1 += exl1; den2 += exl2; den3 += exl3;
  float exh = hsel == 0 ? exl0 : (hsel == 1 ? exl1 : (hsel == 2 ? exl2 : exl3));
  {
    uint2 u = *(const uint2*)(xp + ((size_t)n << 8) + loff);
    float2 fA = __half22float2(*(__half2*)&u.x);
    float2 fB = __half22float2(*(__half2*)&u.y);
    acc0 = fmaf(exh, fA.x, acc0);
    acc1 = fmaf(exh, fA.y, acc1);
    acc2 = fmaf(exh, fB.x, acc2);
    acc3 = fmaf(exh, fB.y, acc3);
  }
  float denh = hsel == 0 ? den0 : (hsel == 1 ? den1 : (hsel == 2 ? den2 : den3));
  float rden = 1.f / (denh + 1e-16f);
  float4 bv = *(const float4*)(bias + (lane << 2));
  __half2 o01 = __floats2half2_rn(fmaxf(acc0 * rden + bv.x, 0.f), fmaxf(acc1 * rden + bv.y, 0.f));
  __half2 o23 = __floats2half2_rn(fmaxf(acc2 * rden + bv.z, 0.f), fmaxf(acc3 * rden + bv.w, 0.f));
  uint2 u;
  u.x = *(unsigned*)&o01;
  u.y = *(unsigned*)&o23;
  *(uint2*)(out + (size_t)n * 256 + (lane << 2)) = u;
}

// ---------------- layer2 (heads=1) + final linear + sigmoid, fused ----------------
__global__ __launch_bounds__(256) void agg1_final(
    const __half* __restrict__ xp, const int* __restrict__ src_sorted,
    const int* __restrict__ row_start, const float* __restrict__ asb,
    const float* __restrict__ adb, const float* __restrict__ ae,
    const float* __restrict__ b2, const float* __restrict__ lin_w,
    const float* __restrict__ lin_b, float* __restrict__ out, int N) {
  __shared__ float sw1[4][64];
  __shared__ int ssrc1[4][64];
  int wave = threadIdx.x >> 6, lane = threadIdx.x & 63;
  int n = blockIdx.x * 4 + wave;
  if (n >= N) return;
  int beg = row_start[n], end = row_start[n + 1];
  int deg = end - beg;
  float adn = adb[n], asn = asb[n];
  float invd = 1.f / fmaxf((float)deg, 1.f);
  float m, al, acc = 0, den = 0;

  if (deg <= 64) {
    int j = beg + lane;
    bool act = j < end;
    int s = 0;
    float aev = 0, asvs = 0;
    if (act) { s = src_sorted[j]; aev = ae[j]; asvs = asb[s]; }
    float l = act ? lrelu(asvs + adn + aev) : -1e30f;
    m = wred_max(l);
    float aes = wred_sum(aev);
    al = lrelu(asn + adn + aes * invd);
    m = fmaxf(m, al);
    float ex = act ? __expf(l - m) : 0.f;
    den = wred_sum(ex);
    sw1[wave][lane] = ex;
    ssrc1[wave][lane] = s;
    asm volatile("" ::: "memory");
    int cnt = deg;
    int sj0 = ssrc1[wave][0], sj1 = ssrc1[wave][1], sj2 = ssrc1[wave][2], sj3 = ssrc1[wave][3];
    __half H0 = xp[((size_t)sj0 << 6) + lane];
    __half H1 = xp[((size_t)sj1 << 6) + lane];
    __half H2 = xp[((size_t)sj2 << 6) + lane];
    __half H3 = xp[((size_t)sj3 << 6) + lane];
    for (int t = 0; t < cnt; t += 4) {
      {
        float w = sw1[wave][t + 0];
        acc = fmaf(w, __half2float(H0), acc);
        int ns = ssrc1[wave][(t + 4) & 63];
        H0 = xp[((size_t)ns << 6) + lane];
      }
      {
        float w = sw1[wave][t + 1];
        acc = fmaf(w, __half2float(H1), acc);
        int ns = ssrc1[wave][(t + 5) & 63];
        H1 = xp[((size_t)ns << 6) + lane];
      }
      {
        float w = sw1[wave][t + 2];
        acc = fmaf(w, __half2float(H2), acc);
        int ns = ssrc1[wave][(t + 6) & 63];
        H2 = xp[((size_t)ns << 6) + lane];
      }
      {
        float w = sw1[wave][t + 3];
        acc = fmaf(w, __half2float(H3), acc);
        int ns = ssrc1[wave][(t + 7) & 63];
        H3 = xp[((size_t)ns << 6) + lane];
      }
    }
  } else {
    m = -1e30f;
    float aes = 0;
    for (int base = beg; base < end; base += 64) {
      int j = base + lane;
      if (j < end) {
        int s = src_sorted[j];
        float aev = ae[j];
        aes += aev;
        m = fmaxf(m, lrelu(asb[s] + adn + aev));
      }
    }
    m = wred_max(m);
    aes = wred_sum(aes);
    al = lrelu(asn + adn + aes * invd);
    m = fmaxf(m, al);
    for (int base = beg; base < end; base += 64) {
      int j = base + lane;
      float ex = 0;
      int s = 0;
      if (j < end) {
        s = src_sorted[j];
        ex = __expf(lrelu(asb[s] + adn + ae[j]) - m);
        den += ex;
      }
      int cnt = min(64, end - base);
      for (int t = 0; t < cnt; ++t) {
        int sj = __shfl(s, t);
        float w = __shfl(ex, t);
        acc = fmaf(w, __half2float(xp[((size_t)sj << 6) + lane]), acc);
      }
    }
    den = wred_sum(den);
  }

  float exl = __expf(al - m);
  den += exl;
  acc = fmaf(exl, __half2float(xp[((size_t)n << 6) + lane]), acc);
  float h = fmaxf(acc / (den + 1e-16f) + b2[lane], 0.f);
  float p = wred_sum(h * lin_w[lane]);
  if (lane == 0) out[n] = 1.f / (1.f + __expf(-(p + lin_b[0])));
}

// ---------------- host glue ----------------
extern "C" void kernel_launch(void* const* d_in, const int* in_sizes, int n_in,
                              void* d_out, int out_size, void* d_ws, size_t ws_size,
                              hipStream_t stream) {
  const float* x    = (const float*)d_in[0];
  const int*   ei   = (const int*)d_in[1];
  const float* ea   = (const float*)d_in[2];
  const float* W0   = (const float*)d_in[3];
  const float* as0w = (const float*)d_in[4];
  const float* ad0w = (const float*)d_in[5];
  const float* We0  = (const float*)d_in[6];
  const float* ae0w = (const float*)d_in[7];
  const float* b0   = (const float*)d_in[8];
  const float* W1   = (const float*)d_in[9];
  const float* as1w = (const float*)d_in[10];
  const float* ad1w = (const float*)d_in[11];
  const float* We1  = (const float*)d_in[12];
  const float* ae1w = (const float*)d_in[13];
  const float* b1   = (const float*)d_in[14];
  const float* W2   = (const float*)d_in[15];
  const float* as2w = (const float*)d_in[16];
  const float* ad2w = (const float*)d_in[17];
  const float* We2  = (const float*)d_in[18];
  const float* ae2w = (const float*)d_in[19];
  const float* b2   = (const float*)d_in[20];
  const float* linw = (const float*)d_in[21];
  const float* linb = (const float*)d_in[22];

  const int N = in_sizes[0] / 128;
  const int E = in_sizes[1] / 2;
  const int* src = ei;
  const int* dst = ei + E;

  char* p = (char*)d_ws;
  auto alloc = [&](size_t bytes) {
    char* r = p;
    p += (bytes + 255) & ~size_t(255);
    return r;
  };
  __half* bufAh      = (__half*)alloc((size_t)N * 256 * 2);
  __half* xph        = (__half*)alloc((size_t)N * 256 * 2);
  __half* W0t        = (__half*)alloc((size_t)256 * 128 * 2);
  __half* W1t        = (__half*)alloc((size_t)256 * 256 * 2);
  __half* W2t        = (__half*)alloc((size_t)64 * 256 * 2);
  float*  asb0       = (float*)alloc((size_t)N * 4 * 4);
  float*  adb0       = (float*)alloc((size_t)N * 4 * 4);
  float*  asb1       = (float*)alloc((size_t)N * 4 * 4);
  float*  adb1       = (float*)alloc((size_t)N * 4 * 4);
  float*  asb2       = (float*)alloc((size_t)N * 4);
  float*  adb2       = (float*)alloc((size_t)N * 4);
  int*    src_sorted = (int*)alloc((size_t)E * 4);
  int*    eid_sorted = (int*)alloc((size_t)E * 4);
  float*  ae0s       = (float*)alloc((size_t)E * 4 * 4);
  float*  ae1s       = (float*)alloc((size_t)E * 4 * 4);
  float*  ae2s       = (float*)alloc((size_t)E * 4);
  int*    deg        = (int*)alloc((size_t)N * 4);
  int*    row_start  = (int*)alloc((size_t)(N + 1) * 4);
  int*    cursor     = (int*)alloc((size_t)N * 4);
  int*    bsum       = (int*)alloc((size_t)256 * 4);
  int*    boff       = (int*)alloc((size_t)256 * 4);
  float*  wv         = (float*)alloc(144 * 4);

  int nb = (N + 255) / 256;
  int eb = (E + 255) / 256;
  zero_all<<<nb, 256, 0, stream>>>(deg, cursor, asb0, adb0, asb1, adb1, asb2, adb2, N);
  count_deg<<<eb, 256, 0, stream>>>(dst, deg, E);
  scan_part<<<nb, 256, 0, stream>>>(deg, bsum, N);
  scan_bsum<<<1, 256, 0, stream>>>(bsum, boff, nb);
  scan_final<<<nb, 256, 0, stream>>>(deg, boff, row_start, N);
  scatter_edges<<<eb, 256, 0, stream>>>(src, dst, row_start, cursor, src_sorted, eid_sorted, E);
  wvec_kernel<<<1, 160, 0, stream>>>(We0, ae0w, We1, ae1w, We2, ae2w, wv);
  edge_ae<<<eb, 256, 0, stream>>>(ea, eid_sorted, wv, ae0s, ae1s, ae2s, E);

  transpose_w_f16<<<dim3(16, 8), 256, 0, stream>>>(W0, W0t, 128, 256);
  transpose_w_f16<<<dim3(16, 16), 256, 0, stream>>>(W1, W1t, 256, 256);
  transpose_w_f16<<<dim3(4, 16), 256, 0, stream>>>(W2, W2t, 256, 64);

  int gm = (N + 127) / 128;
  int nwb = (N + 3) / 4;
  // layer 0 (A = x in f32, converted during staging; fused a_src/a_dst dots)
  gemm_f16mfma<128, true, 4><<<dim3(gm, 2), 256, 0, stream>>>(
      x, W0t, xph, as0w, ad0w, asb0, adb0, N, 128, 256);
  agg_heads4<<<nwb, 256, 0, stream>>>(xph, src_sorted, row_start, asb0, adb0, ae0s, b0, bufAh, N);
  // layer 1
  gemm_f16mfma<128, false, 4><<<dim3(gm, 2), 256, 0, stream>>>(
      bufAh, W1t, xph, as1w, ad1w, asb1, adb1, N, 256, 256);
  agg_heads4<<<nwb, 256, 0, stream>>>(xph, src_sorted, row_start, asb1, adb1, ae1s, b1, bufAh, N);
  // layer 2 + final linear + sigmoid
  gemm_f16mfma<64, false, 1><<<dim3(gm, 1), 256, 0, stream>>>(
      bufAh, W2t, xph, as2w, ad2w, asb2, adb2, N, 256, 64);
  agg1_final<<<nwb, 256, 0, stream>>>(xph, src_sorted, row_start, asb2, adb2, ae2s, b2, linw, linb,
                                      (float*)d_out, N);
}